// Round 3
// baseline (762.630 us; speedup 1.0000x reference)
//
#include <hip/hip_runtime.h>
#include <math.h>

#define T_LEN 8192
#define NUM_CH 64
#define HID 256
#define NUM_CLS 40
#define NUM_PROP 1024
#define NUM_PROP_AFTER 256
#define PROP_LEN 128

#define MS 4        // sequences per group
#define NGRP 64     // sequence groups (NUM_PROP_AFTER / MS)
#define NSL 4       // hidden slices (64 units each)
#define KH 320      // K in halves: 256 h + 64 x
#define KSEGN 4     // K segments per row
#define SEGH 80     // halves per segment

typedef _Float16 h2_t __attribute__((ext_vector_type(2)));
union U32H2 { unsigned int u; h2_t h; };
union HU16 { _Float16 h; unsigned short u; };

#if defined(__has_builtin)
#if __has_builtin(__builtin_amdgcn_fdot2)
#define HAS_FDOT2 1
#endif
#endif

__device__ __forceinline__ float dot2f(unsigned int wa, unsigned int hb, float acc) {
    U32H2 a, b;
    a.u = wa;
    b.u = hb;
#ifdef HAS_FDOT2
    return __builtin_amdgcn_fdot2(a.h, b.h, acc, false);
#else
    return acc + (float)a.h[0] * (float)b.h[0] + (float)a.h[1] * (float)b.h[1];
#endif
}

__device__ __forceinline__ float dot8f(const uint4& w, const uint4& h, float acc) {
    acc = dot2f(w.x, h.x, acc);
    acc = dot2f(w.y, h.y, acc);
    acc = dot2f(w.z, h.z, acc);
    acc = dot2f(w.w, h.w, acc);
    return acc;
}

__device__ __forceinline__ float fsigmoid(float x) { return 1.0f / (1.0f + __expf(-x)); }
__device__ __forceinline__ float ftanh(float x) {
    float e = __expf(-2.0f * fabsf(x));
    float t = (1.0f - e) / (1.0f + e);
    return copysignf(t, x);
}

__device__ __forceinline__ unsigned int pack2(float a, float b) {
    HU16 ha, hb;
    ha.h = (_Float16)a;
    hb.h = (_Float16)b;
    return (unsigned int)ha.u | ((unsigned int)hb.u << 16);
}

// ---------------------------------------------------------------------------
// Single fused cooperative kernel: 256 blocks (4 hid-slices x 64 seq-groups).
//  - block 0 runs NMS (LDS overlaid on pp), publishes t0s + ready flag.
//  - every block loads its W fragment (80 f16 halves/thread) straight from
//    f32 W_ih/W_hh into VGPRs (no pack kernel, no WP buffer).
//  - per step: dot (all 16 waves) | barrier | {waves 0-3: reduce+act+publish
//    +counter-store, waves 4-7: poll 16 counters + gather h(t+1),
//    waves 12-15: x(t+1) prefetch} | barrier.  2 barriers/step, no RMW
//    atomics anywhere, all cross-block traffic relaxed cache-bypassing ops.
// ---------------------------------------------------------------------------
__global__ __launch_bounds__(1024, 4) void fused_kernel(
    const float* __restrict__ data, const float* __restrict__ prop,
    const float* __restrict__ W_ih, const float* __restrict__ W_hh,
    const float* __restrict__ b_ih, const float* __restrict__ b_hh,
    const float* __restrict__ W_cls, const float* __restrict__ b_cls,
    const float* __restrict__ W_bbox, const float* __restrict__ b_bbox,
    float* __restrict__ out, int* __restrict__ t0s,
    unsigned int* __restrict__ Hx, unsigned int* __restrict__ cnt,
    unsigned int* __restrict__ flag) {
    __shared__ __align__(16) _Float16 hx[MS][KH];  // 2.5 KB
    __shared__ __align__(16) float pp[MS][KSEGN][256];  // 16 KB (NMS overlay)

    const int tid = threadIdx.x;
    const int g = blockIdx.x & (NGRP - 1);
    const int s = blockIdx.x >> 6;
    const int kseg = tid >> 8;   // wave-uniform K segment
    const int rl = tid & 255;    // row_local = gate*64 + unit

    // ===================== block 0: NMS =====================
    if (blockIdx.x == 0) {
        float* sc_p = &pp[0][0][0];
        float* ss = &pp[1][0][0];
        float* se = &pp[2][0][0];
        unsigned char* sup = (unsigned char*)&pp[3][0][0];
        unsigned long long* cmask =
            (unsigned long long*)((char*)&pp[3][0][0] + 1024);

        float ps = prop[tid * 3 + 0];
        float pe = prop[tid * 3 + 1];
        float pc = prop[tid * 3 + 2];
        sc_p[tid] = pc;
        sup[tid] = 0;
        __syncthreads();

        int r = 0;
        for (int j = 0; j < NUM_PROP; ++j) {
            float o = sc_p[j];
            r += (o > pc) || (o == pc && j < tid);
        }
        ss[r] = ps;
        se[r] = pe;
        __syncthreads();

        const float my_s = ss[tid];
        const float my_e = se[tid];
        const float my_len = my_e - my_s;
        bool mysup = false;

        for (int ci = 0; ci < 16; ++ci) {
            if (tid < 64) {
                int i = ci * 64 + tid;
                float is_ = ss[i], ie_ = se[i];
                unsigned long long m = __ballot(sup[i] != 0);
                for (int l = 0; l < 64; ++l) {
                    if (!((m >> l) & 1)) {
                        float ls = __shfl(is_, l);
                        float le = __shfl(ie_, l);
                        float inter = fmaxf(fminf(le, ie_) - fmaxf(ls, is_), 0.0f);
                        float uni = (le - ls) + (ie_ - is_) - inter;
                        float iou = inter / fmaxf(uni, 1e-6f);
                        unsigned long long nb = __ballot((tid > l) && (iou > 0.5f));
                        m |= nb;
                    }
                }
                sup[i] = (unsigned char)((m >> tid) & 1);
                if (tid == 0) cmask[ci] = ~m;
            }
            __syncthreads();
            unsigned long long am = cmask[ci];
            for (int l = 0; l < 64; ++l) {
                if ((am >> l) & 1) {
                    int i = ci * 64 + l;
                    if (tid > i && !mysup) {
                        float ls = ss[i], le = se[i];
                        float inter = fmaxf(fminf(le, my_e) - fmaxf(ls, my_s), 0.0f);
                        float uni = (le - ls) + my_len - inter;
                        if (inter / fmaxf(uni, 1e-6f) > 0.5f) mysup = true;
                    }
                }
            }
            sup[tid] = mysup ? 1 : 0;
            __syncthreads();
        }

        int myc = tid >> 6;
        unsigned long long mybit = 1ull << (tid & 63);
        int kb = 0, kt = 0;
        for (int c2 = 0; c2 < 16; ++c2) {
            int p = __popcll(cmask[c2]);
            kt += p;
            if (c2 < myc) kb += p;
        }
        kb += __popcll(cmask[myc] & (mybit - 1));
        int slot = (cmask[myc] & mybit) ? kb : (kt + (tid - kb));
        if (slot < NUM_PROP_AFTER) {
            int t0v = (int)rintf(my_s);
            t0v = max(0, min(t0v, T_LEN - PROP_LEN));
            __hip_atomic_store(&t0s[slot], t0v, __ATOMIC_RELAXED,
                               __HIP_MEMORY_SCOPE_AGENT);
        }
        asm volatile("s_waitcnt vmcnt(0)" ::: "memory");
        __syncthreads();
        if (tid == 0)
            __hip_atomic_store(flag, 1u, __ATOMIC_RELAXED,
                               __HIP_MEMORY_SCOPE_AGENT);
        __syncthreads();
    }

    // ============ W fragment: direct f32 load + f16 pack ============
    uint4 Wr[10];
    {
        const int gate = rl >> 6, unit = rl & 63;
        const int grow = gate * 256 + s * 64 + unit;
        const float* __restrict__ baseh = W_hh + grow * HID;
        const float* __restrict__ basex = W_ih + grow * NUM_CH;
#pragma unroll
        for (int j = 0; j < 10; ++j) {
            const int kh = kseg * SEGH + j * 8;
            const float* src = (kh < 256) ? (baseh + kh) : (basex + (kh - 256));
            float4 f0 = *(const float4*)(src);
            float4 f1 = *(const float4*)(src + 4);
            Wr[j] = make_uint4(pack2(f0.x, f0.y), pack2(f0.z, f0.w),
                               pack2(f1.x, f1.y), pack2(f1.z, f1.w));
        }
    }

    // epilogue role (tid<256): wave aq = seq, lane au = unit
    const int aq = tid >> 6;
    const int au = tid & 63;
    float bi = 0.f, bf = 0.f, bg = 0.f, bo = 0.f, c_st = 0.f;
    if (tid < 256) {
        int u = s * 64 + au;
        bi = b_ih[u] + b_hh[u];
        bf = b_ih[256 + u] + b_hh[256 + u];
        bg = b_ih[512 + u] + b_hh[512 + u];
        bo = b_ih[768 + u] + b_hh[768 + u];
    }

    // zero h region of hx
    hx[tid >> 8][tid & 255] = (_Float16)0.0f;

    // wait for t0s-ready flag
    if (tid == 0) {
        while (__hip_atomic_load(flag, __ATOMIC_RELAXED,
                                 __HIP_MEMORY_SCOPE_AGENT) == 0u) {
            __builtin_amdgcn_s_sleep(4);
        }
    }
    __syncthreads();

    // x role (waves 12-15): seq xs, channel xch
    const int xs = (tid >> 6) & 3;
    const int xch = tid & 63;
    int xt0 = 0;
    if (tid >= 768) {
        xt0 = __hip_atomic_load(&t0s[g * MS + xs], __ATOMIC_RELAXED,
                                __HIP_MEMORY_SCOPE_AGENT);
        hx[xs][256 + xch] = (_Float16)data[xt0 * NUM_CH + xch];  // x(0)
    }

    unsigned short* HxH = (unsigned short*)Hx;
    unsigned long long* Hx64 = (unsigned long long*)Hx;
    unsigned int* cg = &cnt[g * 16];  // 16 dwords = one 64B line per group
    const int pi = tid & 15;          // poll lane -> counter index
    __syncthreads();

    for (int t = 0; t < PROP_LEN; ++t) {
        // --- dot: 4 accumulator chains, broadcast LDS reads ---
        float a0 = 0.f, a1 = 0.f, a2 = 0.f, a3 = 0.f;
#pragma unroll
        for (int j = 0; j < 10; ++j) {
            const int hb = kseg * SEGH + j * 8;
            uint4 h0 = *(const uint4*)&hx[0][hb];
            uint4 h1 = *(const uint4*)&hx[1][hb];
            uint4 h2 = *(const uint4*)&hx[2][hb];
            uint4 h3 = *(const uint4*)&hx[3][hb];
            uint4 w = Wr[j];
            a0 = dot8f(w, h0, a0);
            a1 = dot8f(w, h1, a1);
            a2 = dot8f(w, h2, a2);
            a3 = dot8f(w, h3, a3);
        }
        pp[0][kseg][rl] = a0;
        pp[1][kseg][rl] = a1;
        pp[2][kseg][rl] = a2;
        pp[3][kseg][rl] = a3;
        __syncthreads();

        const unsigned int tgt = (unsigned int)(t + 1);
        if (tid < 256) {
            // --- reduce + activation + publish + counter store ---
            float si = pp[aq][0][au] + pp[aq][1][au] + pp[aq][2][au] +
                       pp[aq][3][au] + bi;
            float sf = pp[aq][0][64 + au] + pp[aq][1][64 + au] +
                       pp[aq][2][64 + au] + pp[aq][3][64 + au] + bf;
            float sg = pp[aq][0][128 + au] + pp[aq][1][128 + au] +
                       pp[aq][2][128 + au] + pp[aq][3][128 + au] + bg;
            float so = pp[aq][0][192 + au] + pp[aq][1][192 + au] +
                       pp[aq][2][192 + au] + pp[aq][3][192 + au] + bo;
            float gi = fsigmoid(si), gf = fsigmoid(sf);
            float gg = ftanh(sg), go = fsigmoid(so);
            c_st = gf * c_st + gi * gg;
            float h = go * ftanh(c_st);
            HU16 hu;
            hu.h = (_Float16)h;
            __hip_atomic_store(
                &HxH[((((t + 1) & 1) * NGRP + g) * MS + aq) * 256 + s * 64 + au],
                hu.u, __ATOMIC_RELAXED, __HIP_MEMORY_SCOPE_AGENT);
            asm volatile("s_waitcnt vmcnt(0)" ::: "memory");  // drain this wave's stores
            if (au == 0)
                __hip_atomic_store(&cg[s * 4 + aq], tgt, __ATOMIC_RELAXED,
                                   __HIP_MEMORY_SCOPE_AGENT);
        } else if (tid < 512) {
            // --- poll all 16 counters (one 64B line), then gather h(t+1) ---
            unsigned int v;
            do {
                v = __hip_atomic_load(&cg[pi], __ATOMIC_RELAXED,
                                      __HIP_MEMORY_SCOPE_AGENT);
            } while (__any(v < tgt));
            int gi2 = tid - 256;          // 0..255
            int sq = gi2 >> 6, w2 = gi2 & 63;
            unsigned long long hv = __hip_atomic_load(
                &Hx64[((((t + 1) & 1) * NGRP + g) * MS + sq) * 64 + w2],
                __ATOMIC_RELAXED, __HIP_MEMORY_SCOPE_AGENT);
            ((unsigned long long*)&hx[sq][0])[w2] = hv;
        } else if (tid >= 768) {
            // --- prefetch x(t+1) ---
            if (t + 1 < PROP_LEN)
                hx[xs][256 + xch] = (_Float16)data[(xt0 + t + 1) * NUM_CH + xch];
        }
        __syncthreads();
    }

    // hx holds h_128 for all 4 seqs. Slice s computes rows [30s, 30s+30).
    if (tid < MS * 30) {
        int sq = tid / 30;
        int ml = tid % 30;
        int m = s * 30 + ml;
        const float* Wrow;
        float acc;
        int oidx;
        if (m < NUM_CLS) {
            Wrow = W_cls + m * HID;
            acc = b_cls[m];
            oidx = (g * MS + sq) * NUM_CLS + m;
        } else {
            int mb = m - NUM_CLS;
            Wrow = W_bbox + mb * HID;
            acc = b_bbox[mb];
            oidx = NUM_PROP_AFTER * NUM_CLS + (g * MS + sq) * 2 * NUM_CLS + mb;
        }
        const float4* w4 = (const float4*)Wrow;
        const _Float16* hp = &hx[sq][0];
        for (int c = 0; c < 32; ++c) {
            float4 wa = w4[c * 2 + 0];
            float4 wb = w4[c * 2 + 1];
            acc += (float)hp[c * 8 + 0] * wa.x + (float)hp[c * 8 + 1] * wa.y +
                   (float)hp[c * 8 + 2] * wa.z + (float)hp[c * 8 + 3] * wa.w +
                   (float)hp[c * 8 + 4] * wb.x + (float)hp[c * 8 + 5] * wb.y +
                   (float)hp[c * 8 + 6] * wb.z + (float)hp[c * 8 + 7] * wb.w;
        }
        out[oidx] = acc;
    }
}

extern "C" void kernel_launch(void* const* d_in, const int* in_sizes, int n_in,
                              void* d_out, int out_size, void* d_ws,
                              size_t ws_size, hipStream_t stream) {
    const float* data = (const float*)d_in[0];     // [8192, 64]
    const float* prop = (const float*)d_in[1];     // [1024, 3]
    const float* W_ih = (const float*)d_in[2];     // [1024, 64]
    const float* W_hh = (const float*)d_in[3];     // [1024, 256]
    const float* b_ih = (const float*)d_in[4];     // [1024]
    const float* b_hh = (const float*)d_in[5];     // [1024]
    const float* W_cls = (const float*)d_in[6];    // [40, 256]
    const float* b_cls = (const float*)d_in[7];    // [40]
    const float* W_bbox = (const float*)d_in[8];   // [80, 256]
    const float* b_bbox = (const float*)d_in[9];   // [80]
    float* out = (float*)d_out;

    // workspace layout
    int* t0s = (int*)d_ws;                                          // 1 KB
    unsigned int* Hx = (unsigned int*)((char*)d_ws + 1024);         // 256 KB exchange
    unsigned int* cnt = (unsigned int*)((char*)d_ws + 263168);      // 4 KB counters
    unsigned int* flag = (unsigned int*)((char*)d_ws + 267264);     // 4 B flag

    // zero counters + flag each invocation (graph-captured, replayed per rep)
    hipMemsetAsync((char*)d_ws + 263168, 0, 4096 + 64, stream);

    void* kargs[] = {(void*)&data,  (void*)&prop,   (void*)&W_ih,  (void*)&W_hh,
                     (void*)&b_ih,  (void*)&b_hh,   (void*)&W_cls, (void*)&b_cls,
                     (void*)&W_bbox, (void*)&b_bbox, (void*)&out,  (void*)&t0s,
                     (void*)&Hx,    (void*)&cnt,    (void*)&flag};
    hipLaunchCooperativeKernel((void*)fused_kernel, dim3(NSL * NGRP), dim3(1024),
                               kargs, 0, stream);
}

// Round 4
// 746.299 us; speedup vs baseline: 1.0219x; 1.0219x over previous
//
#include <hip/hip_runtime.h>
#include <math.h>

#define T_LEN 8192
#define NUM_CH 64
#define HID 256
#define NUM_CLS 40
#define NUM_PROP 1024
#define NUM_PROP_AFTER 256
#define PROP_LEN 128

#define MS 4        // sequences per group
#define NGRP 64     // sequence groups (NUM_PROP_AFTER / MS)
#define NSL 4       // hidden slices (64 units each)
#define KH 320      // K in halves: 256 h + 64 x
#define KSEGN 4     // K segments per row
#define SEGH 80     // halves per segment

typedef _Float16 h2_t __attribute__((ext_vector_type(2)));
union U32H2 { unsigned int u; h2_t h; };
union HU16 { _Float16 h; unsigned short u; };

#if defined(__has_builtin)
#if __has_builtin(__builtin_amdgcn_fdot2)
#define HAS_FDOT2 1
#endif
#endif

__device__ __forceinline__ float dot2f(unsigned int wa, unsigned int hb, float acc) {
    U32H2 a, b;
    a.u = wa;
    b.u = hb;
#ifdef HAS_FDOT2
    return __builtin_amdgcn_fdot2(a.h, b.h, acc, false);
#else
    return acc + (float)a.h[0] * (float)b.h[0] + (float)a.h[1] * (float)b.h[1];
#endif
}

__device__ __forceinline__ float dot8f(const uint4& w, const uint4& h, float acc) {
    acc = dot2f(w.x, h.x, acc);
    acc = dot2f(w.y, h.y, acc);
    acc = dot2f(w.z, h.z, acc);
    acc = dot2f(w.w, h.w, acc);
    return acc;
}

__device__ __forceinline__ float fsigmoid(float x) { return 1.0f / (1.0f + __expf(-x)); }
__device__ __forceinline__ float ftanh(float x) {
    float e = __expf(-2.0f * fabsf(x));
    float t = (1.0f - e) / (1.0f + e);
    return copysignf(t, x);
}

__device__ __forceinline__ unsigned int pack2(float a, float b) {
    HU16 ha, hb;
    ha.h = (_Float16)a;
    hb.h = (_Float16)b;
    return (unsigned int)ha.u | ((unsigned int)hb.u << 16);
}

// ---------------------------------------------------------------------------
// Single fused cooperative kernel: 256 blocks (4 hid-slices x 64 seq-groups).
//  - block 0 runs NMS (LDS overlaid on pp), publishes t0s with bit31 tag.
//  - every block loads its W fragment (80 f16 halves/thread) straight from
//    f32 W_ih/W_hh into VGPRs (no pack kernel).
//  - loop = R2's PROVEN structure (459us): 3 barriers/step,
//    drain -> fire-and-forget fetch_add, single tid0 sleep-poll of one
//    cumulative counter, 512-thread gather, x-prefetch on waves 8-11.
// ---------------------------------------------------------------------------
__global__ __launch_bounds__(1024, 4) void fused_kernel(
    const float* __restrict__ data, const float* __restrict__ prop,
    const float* __restrict__ W_ih, const float* __restrict__ W_hh,
    const float* __restrict__ b_ih, const float* __restrict__ b_hh,
    const float* __restrict__ W_cls, const float* __restrict__ b_cls,
    const float* __restrict__ W_bbox, const float* __restrict__ b_bbox,
    float* __restrict__ out, unsigned int* __restrict__ t0s,
    unsigned int* __restrict__ Hx, unsigned int* __restrict__ cnt) {
    __shared__ __align__(16) _Float16 hx[MS][KH];       // 2.5 KB
    __shared__ __align__(16) float pp[MS][KSEGN][256];  // 16 KB (NMS overlay)

    const int tid = threadIdx.x;
    const int g = blockIdx.x & (NGRP - 1);
    const int s = blockIdx.x >> 6;
    const int kseg = tid >> 8;   // wave-uniform K segment
    const int rl = tid & 255;    // row_local = gate*64 + unit

    // ===================== block 0: NMS =====================
    if (blockIdx.x == 0) {
        float* sc_p = &pp[0][0][0];
        float* ss = &pp[1][0][0];
        float* se = &pp[2][0][0];
        unsigned char* sup = (unsigned char*)&pp[3][0][0];
        unsigned long long* cmask =
            (unsigned long long*)((char*)&pp[3][0][0] + 1024);

        float ps = prop[tid * 3 + 0];
        float pe = prop[tid * 3 + 1];
        float pc = prop[tid * 3 + 2];
        sc_p[tid] = pc;
        sup[tid] = 0;
        __syncthreads();

        int r = 0;
        for (int j = 0; j < NUM_PROP; ++j) {
            float o = sc_p[j];
            r += (o > pc) || (o == pc && j < tid);
        }
        ss[r] = ps;
        se[r] = pe;
        __syncthreads();

        const float my_s = ss[tid];
        const float my_e = se[tid];
        const float my_len = my_e - my_s;
        bool mysup = false;

        for (int ci = 0; ci < 16; ++ci) {
            if (tid < 64) {
                int i = ci * 64 + tid;
                float is_ = ss[i], ie_ = se[i];
                unsigned long long m = __ballot(sup[i] != 0);
                for (int l = 0; l < 64; ++l) {
                    if (!((m >> l) & 1)) {
                        float ls = __shfl(is_, l);
                        float le = __shfl(ie_, l);
                        float inter = fmaxf(fminf(le, ie_) - fmaxf(ls, is_), 0.0f);
                        float uni = (le - ls) + (ie_ - is_) - inter;
                        float iou = inter / fmaxf(uni, 1e-6f);
                        unsigned long long nb = __ballot((tid > l) && (iou > 0.5f));
                        m |= nb;
                    }
                }
                sup[i] = (unsigned char)((m >> tid) & 1);
                if (tid == 0) cmask[ci] = ~m;
            }
            __syncthreads();
            unsigned long long am = cmask[ci];
            for (int l = 0; l < 64; ++l) {
                if ((am >> l) & 1) {
                    int i = ci * 64 + l;
                    if (tid > i && !mysup) {
                        float ls = ss[i], le = se[i];
                        float inter = fmaxf(fminf(le, my_e) - fmaxf(ls, my_s), 0.0f);
                        float uni = (le - ls) + my_len - inter;
                        if (inter / fmaxf(uni, 1e-6f) > 0.5f) mysup = true;
                    }
                }
            }
            sup[tid] = mysup ? 1 : 0;
            __syncthreads();
        }

        int myc = tid >> 6;
        unsigned long long mybit = 1ull << (tid & 63);
        int kb = 0, kt = 0;
        for (int c2 = 0; c2 < 16; ++c2) {
            int p = __popcll(cmask[c2]);
            kt += p;
            if (c2 < myc) kb += p;
        }
        kb += __popcll(cmask[myc] & (mybit - 1));
        int slot = (cmask[myc] & mybit) ? kb : (kt + (tid - kb));
        if (slot < NUM_PROP_AFTER) {
            int t0v = (int)rintf(my_s);
            t0v = max(0, min(t0v, T_LEN - PROP_LEN));
            __hip_atomic_store(&t0s[slot], (unsigned int)t0v | 0x80000000u,
                               __ATOMIC_RELAXED, __HIP_MEMORY_SCOPE_AGENT);
        }
        asm volatile("s_waitcnt vmcnt(0)" ::: "memory");
        __syncthreads();
    }

    // ============ W fragment: direct f32 load + f16 pack ============
    uint4 Wr[10];
    {
        const int gate = rl >> 6, unit = rl & 63;
        const int grow = gate * 256 + s * 64 + unit;
        const float* __restrict__ baseh = W_hh + grow * HID;
        const float* __restrict__ basex = W_ih + grow * NUM_CH;
#pragma unroll
        for (int j = 0; j < 10; ++j) {
            const int kh = kseg * SEGH + j * 8;
            const float* src = (kh < 256) ? (baseh + kh) : (basex + (kh - 256));
            float4 f0 = *(const float4*)(src);
            float4 f1 = *(const float4*)(src + 4);
            Wr[j] = make_uint4(pack2(f0.x, f0.y), pack2(f0.z, f0.w),
                               pack2(f1.x, f1.y), pack2(f1.z, f1.w));
        }
    }

    // epilogue role (tid<256): wave aq = seq, lane au = unit
    const int aq = tid >> 6;
    const int au = tid & 63;
    float bi = 0.f, bf = 0.f, bg = 0.f, bo = 0.f, c_st = 0.f;
    if (tid < 256) {
        int u = s * 64 + au;
        bi = b_ih[u] + b_hh[u];
        bf = b_ih[256 + u] + b_hh[256 + u];
        bg = b_ih[512 + u] + b_hh[512 + u];
        bo = b_ih[768 + u] + b_hh[768 + u];
    }

    // zero h region of hx
    hx[tid >> 8][tid & 255] = (_Float16)0.0f;

    // x role (waves 8-11): seq xs, channel xch.  Poll tagged t0s (only these
    // 4 waves poll; s_sleep(8) backoff keeps coherence-point pressure low).
    const int xs = (tid >> 6) & 3;
    const int xch = tid & 63;
    int xt0 = 0;
    if (tid >= 512 && tid < 768) {
        const unsigned int* tp = &t0s[g * MS + xs];
        unsigned int tv;
        for (;;) {
            tv = __hip_atomic_load(tp, __ATOMIC_RELAXED, __HIP_MEMORY_SCOPE_AGENT);
            if (tv & 0x80000000u) break;
            __builtin_amdgcn_s_sleep(8);
        }
        xt0 = (int)(tv & 0x7FFFFFFFu);
        hx[xs][256 + xch] = (_Float16)data[xt0 * NUM_CH + xch];  // x(0)
    }

    unsigned short* HxH = (unsigned short*)Hx;
    unsigned int* cg = &cnt[g * 16];  // one 64B line per group
    __syncthreads();  // waits for x(0) + NMS handoff

    for (int t = 0; t < PROP_LEN; ++t) {
        // --- dot: 4 accumulator chains, broadcast LDS reads ---
        float a0 = 0.f, a1 = 0.f, a2 = 0.f, a3 = 0.f;
#pragma unroll
        for (int j = 0; j < 10; ++j) {
            const int hb = kseg * SEGH + j * 8;
            uint4 h0 = *(const uint4*)&hx[0][hb];
            uint4 h1 = *(const uint4*)&hx[1][hb];
            uint4 h2 = *(const uint4*)&hx[2][hb];
            uint4 h3 = *(const uint4*)&hx[3][hb];
            uint4 w = Wr[j];
            a0 = dot8f(w, h0, a0);
            a1 = dot8f(w, h1, a1);
            a2 = dot8f(w, h2, a2);
            a3 = dot8f(w, h3, a3);
        }
        pp[0][kseg][rl] = a0;
        pp[1][kseg][rl] = a1;
        pp[2][kseg][rl] = a2;
        pp[3][kseg][rl] = a3;
        __syncthreads();

        // --- fused reduce + activation + publish (waves 0-3) ---
        if (tid < 256) {
            float si = pp[aq][0][au] + pp[aq][1][au] + pp[aq][2][au] +
                       pp[aq][3][au] + bi;
            float sf = pp[aq][0][64 + au] + pp[aq][1][64 + au] +
                       pp[aq][2][64 + au] + pp[aq][3][64 + au] + bf;
            float sg = pp[aq][0][128 + au] + pp[aq][1][128 + au] +
                       pp[aq][2][128 + au] + pp[aq][3][128 + au] + bg;
            float so = pp[aq][0][192 + au] + pp[aq][1][192 + au] +
                       pp[aq][2][192 + au] + pp[aq][3][192 + au] + bo;
            float gi = fsigmoid(si), gf = fsigmoid(sf);
            float gg = ftanh(sg), go = fsigmoid(so);
            c_st = gf * c_st + gi * gg;
            float h = go * ftanh(c_st);
            HU16 hu;
            hu.h = (_Float16)h;
            __hip_atomic_store(
                &HxH[((((t + 1) & 1) * NGRP + g) * MS + aq) * 256 + s * 64 + au],
                hu.u, __ATOMIC_RELAXED, __HIP_MEMORY_SCOPE_AGENT);
            // wave-local drain: stores acked at coherence point before the add
            asm volatile("s_waitcnt vmcnt(0)" ::: "memory");
            if (au == 0)
                __hip_atomic_fetch_add(cg, 1u, __ATOMIC_RELAXED,
                                       __HIP_MEMORY_SCOPE_AGENT);
        } else if (tid < 768 && t + 1 < PROP_LEN) {
            // prefetch x(t+1) on waves 8-11 (x region not read this phase)
            hx[xs][256 + xch] = (_Float16)data[(xt0 + t + 1) * NUM_CH + xch];
        }

        // --- wait for all 16 wave-adds of this step, then gather h(t+1) ---
        const unsigned int tgt = 16u * (unsigned int)(t + 1);
        if (tid == 0) {
            while (__hip_atomic_load(cg, __ATOMIC_RELAXED,
                                     __HIP_MEMORY_SCOPE_AGENT) < tgt) {
                __builtin_amdgcn_s_sleep(1);
            }
        }
        __syncthreads();
        if (tid < 512) {
            int sq = tid >> 7, w = tid & 127;
            unsigned int v = __hip_atomic_load(
                &Hx[((((t + 1) & 1) * NGRP + g) * MS + sq) * 128 + w],
                __ATOMIC_RELAXED, __HIP_MEMORY_SCOPE_AGENT);
            ((unsigned int*)hx)[sq * 160 + w] = v;
        }
        __syncthreads();
    }

    // hx holds h_128 for all 4 seqs. Slice s computes rows [30s, 30s+30).
    if (tid < MS * 30) {
        int sq = tid / 30;
        int ml = tid % 30;
        int m = s * 30 + ml;
        const float* Wrow;
        float acc;
        int oidx;
        if (m < NUM_CLS) {
            Wrow = W_cls + m * HID;
            acc = b_cls[m];
            oidx = (g * MS + sq) * NUM_CLS + m;
        } else {
            int mb = m - NUM_CLS;
            Wrow = W_bbox + mb * HID;
            acc = b_bbox[mb];
            oidx = NUM_PROP_AFTER * NUM_CLS + (g * MS + sq) * 2 * NUM_CLS + mb;
        }
        const float4* w4 = (const float4*)Wrow;
        const _Float16* hp = &hx[sq][0];
        for (int c = 0; c < 32; ++c) {
            float4 wa = w4[c * 2 + 0];
            float4 wb = w4[c * 2 + 1];
            acc += (float)hp[c * 8 + 0] * wa.x + (float)hp[c * 8 + 1] * wa.y +
                   (float)hp[c * 8 + 2] * wa.z + (float)hp[c * 8 + 3] * wa.w +
                   (float)hp[c * 8 + 4] * wb.x + (float)hp[c * 8 + 5] * wb.y +
                   (float)hp[c * 8 + 6] * wb.z + (float)hp[c * 8 + 7] * wb.w;
        }
        out[oidx] = acc;
    }
}

extern "C" void kernel_launch(void* const* d_in, const int* in_sizes, int n_in,
                              void* d_out, int out_size, void* d_ws,
                              size_t ws_size, hipStream_t stream) {
    const float* data = (const float*)d_in[0];     // [8192, 64]
    const float* prop = (const float*)d_in[1];     // [1024, 3]
    const float* W_ih = (const float*)d_in[2];     // [1024, 64]
    const float* W_hh = (const float*)d_in[3];     // [1024, 256]
    const float* b_ih = (const float*)d_in[4];     // [1024]
    const float* b_hh = (const float*)d_in[5];     // [1024]
    const float* W_cls = (const float*)d_in[6];    // [40, 256]
    const float* b_cls = (const float*)d_in[7];    // [40]
    const float* W_bbox = (const float*)d_in[8];   // [80, 256]
    const float* b_bbox = (const float*)d_in[9];   // [80]
    float* out = (float*)d_out;

    // workspace layout
    unsigned int* t0s = (unsigned int*)d_ws;                     // [0, 1KB)   tagged t0s
    unsigned int* cnt = (unsigned int*)((char*)d_ws + 1024);     // [1KB, 5KB) counters
    unsigned int* Hx = (unsigned int*)((char*)d_ws + 5120);      // [5KB, 261KB) exchange

    // zero tagged t0s + counters each invocation (graph-captured per rep)
    hipMemsetAsync(d_ws, 0, 5120, stream);

    void* kargs[] = {(void*)&data,  (void*)&prop,   (void*)&W_ih,  (void*)&W_hh,
                     (void*)&b_ih,  (void*)&b_hh,   (void*)&W_cls, (void*)&b_cls,
                     (void*)&W_bbox, (void*)&b_bbox, (void*)&out,  (void*)&t0s,
                     (void*)&Hx,    (void*)&cnt};
    hipLaunchCooperativeKernel((void*)fused_kernel, dim3(NSL * NGRP), dim3(1024),
                               kargs, 0, stream);
}

// Round 5
// 635.736 us; speedup vs baseline: 1.1996x; 1.1739x over previous
//
#include <hip/hip_runtime.h>
#include <math.h>

#define T_LEN 8192
#define NUM_CH 64
#define HID 256
#define NUM_CLS 40
#define NUM_PROP 1024
#define NUM_PROP_AFTER 256
#define PROP_LEN 128

#define MS 4        // sequences per group
#define NGRP 64     // sequence groups (NUM_PROP_AFTER / MS)
#define NSL 4       // hidden slices (64 units each)
#define KH 320      // K in halves: 256 h + 64 x
#define KSEGN 4     // K segments per row
#define SEGH 80     // halves per segment
#define HXPAR 65536 // u32s per parity buffer: 256 seqs x 256 units

typedef _Float16 h2_t __attribute__((ext_vector_type(2)));
union U32H2 { unsigned int u; h2_t h; };
union HU16 { _Float16 h; unsigned short u; };

#if defined(__has_builtin)
#if __has_builtin(__builtin_amdgcn_fdot2)
#define HAS_FDOT2 1
#endif
#endif

__device__ __forceinline__ float dot2f(unsigned int wa, unsigned int hb, float acc) {
    U32H2 a, b;
    a.u = wa;
    b.u = hb;
#ifdef HAS_FDOT2
    return __builtin_amdgcn_fdot2(a.h, b.h, acc, false);
#else
    return acc + (float)a.h[0] * (float)b.h[0] + (float)a.h[1] * (float)b.h[1];
#endif
}

__device__ __forceinline__ float dot8f(const uint4& w, const uint4& h, float acc) {
    acc = dot2f(w.x, h.x, acc);
    acc = dot2f(w.y, h.y, acc);
    acc = dot2f(w.z, h.z, acc);
    acc = dot2f(w.w, h.w, acc);
    return acc;
}

__device__ __forceinline__ float fsigmoid(float x) { return 1.0f / (1.0f + __expf(-x)); }
__device__ __forceinline__ float ftanh(float x) {
    float e = __expf(-2.0f * fabsf(x));
    float t = (1.0f - e) / (1.0f + e);
    return copysignf(t, x);
}

__device__ __forceinline__ unsigned int pack2(float a, float b) {
    HU16 ha, hb;
    ha.h = (_Float16)a;
    hb.h = (_Float16)b;
    return (unsigned int)ha.u | ((unsigned int)hb.u << 16);
}

// ---------------------------------------------------------------------------
// Single fused cooperative kernel: 256 blocks (4 hid-slices x 64 seq-groups).
//  - block 0 runs NMS (LDS overlaid on pp), publishes t0s with bit31 tag.
//  - every block loads its W fragment straight from f32 W into VGPRs.
//  - h exchange is TAGGED DATA: each h published as u32 (tag<<16 | f16),
//    tag = t+1 (unique per step within a rep), double-buffered by parity.
//    Consumers retry-load until tag matches: the gather IS the sync --
//    no counters, no RMW, no vmcnt drains, no fences. Double-buffering +
//    the step dependency chain guarantee no overwrite-before-read.
//  - roles/step: all 16 waves dot | barrier | waves 0-3 reduce+act+publish
//    (+early-issued x(t+1) write), waves 4-15 gather 768 peer words | barrier.
// ---------------------------------------------------------------------------
__global__ __launch_bounds__(1024, 4) void fused_kernel(
    const float* __restrict__ data, const float* __restrict__ prop,
    const float* __restrict__ W_ih, const float* __restrict__ W_hh,
    const float* __restrict__ b_ih, const float* __restrict__ b_hh,
    const float* __restrict__ W_cls, const float* __restrict__ b_cls,
    const float* __restrict__ W_bbox, const float* __restrict__ b_bbox,
    float* __restrict__ out, unsigned int* __restrict__ t0s,
    unsigned int* __restrict__ Hx32) {
    __shared__ __align__(16) _Float16 hx[MS][KH];       // 2.5 KB
    __shared__ __align__(16) float pp[MS][KSEGN][256];  // 16 KB (NMS overlay)

    const int tid = threadIdx.x;
    const int g = blockIdx.x & (NGRP - 1);
    const int s = blockIdx.x >> 6;
    const int kseg = tid >> 8;   // wave-uniform K segment
    const int rl = tid & 255;    // row_local = gate*64 + unit

    // ===================== block 0: NMS =====================
    if (blockIdx.x == 0) {
        float* sc_p = &pp[0][0][0];
        float* ss = &pp[1][0][0];
        float* se = &pp[2][0][0];
        unsigned char* sup = (unsigned char*)&pp[3][0][0];
        unsigned long long* cmask =
            (unsigned long long*)((char*)&pp[3][0][0] + 1024);

        float ps = prop[tid * 3 + 0];
        float pe = prop[tid * 3 + 1];
        float pc = prop[tid * 3 + 2];
        sc_p[tid] = pc;
        sup[tid] = 0;
        __syncthreads();

        int r = 0;
        for (int j = 0; j < NUM_PROP; ++j) {
            float o = sc_p[j];
            r += (o > pc) || (o == pc && j < tid);
        }
        ss[r] = ps;
        se[r] = pe;
        __syncthreads();

        const float my_s = ss[tid];
        const float my_e = se[tid];
        const float my_len = my_e - my_s;
        bool mysup = false;

        for (int ci = 0; ci < 16; ++ci) {
            if (tid < 64) {
                int i = ci * 64 + tid;
                float is_ = ss[i], ie_ = se[i];
                unsigned long long m = __ballot(sup[i] != 0);
                for (int l = 0; l < 64; ++l) {
                    if (!((m >> l) & 1)) {
                        float ls = __shfl(is_, l);
                        float le = __shfl(ie_, l);
                        float inter = fmaxf(fminf(le, ie_) - fmaxf(ls, is_), 0.0f);
                        float uni = (le - ls) + (ie_ - is_) - inter;
                        float iou = inter / fmaxf(uni, 1e-6f);
                        unsigned long long nb = __ballot((tid > l) && (iou > 0.5f));
                        m |= nb;
                    }
                }
                sup[i] = (unsigned char)((m >> tid) & 1);
                if (tid == 0) cmask[ci] = ~m;
            }
            __syncthreads();
            unsigned long long am = cmask[ci];
            for (int l = 0; l < 64; ++l) {
                if ((am >> l) & 1) {
                    int i = ci * 64 + l;
                    if (tid > i && !mysup) {
                        float ls = ss[i], le = se[i];
                        float inter = fmaxf(fminf(le, my_e) - fmaxf(ls, my_s), 0.0f);
                        float uni = (le - ls) + my_len - inter;
                        if (inter / fmaxf(uni, 1e-6f) > 0.5f) mysup = true;
                    }
                }
            }
            sup[tid] = mysup ? 1 : 0;
            __syncthreads();
        }

        int myc = tid >> 6;
        unsigned long long mybit = 1ull << (tid & 63);
        int kb = 0, kt = 0;
        for (int c2 = 0; c2 < 16; ++c2) {
            int p = __popcll(cmask[c2]);
            kt += p;
            if (c2 < myc) kb += p;
        }
        kb += __popcll(cmask[myc] & (mybit - 1));
        int slot = (cmask[myc] & mybit) ? kb : (kt + (tid - kb));
        if (slot < NUM_PROP_AFTER) {
            int t0v = (int)rintf(my_s);
            t0v = max(0, min(t0v, T_LEN - PROP_LEN));
            __hip_atomic_store(&t0s[slot], (unsigned int)t0v | 0x80000000u,
                               __ATOMIC_RELAXED, __HIP_MEMORY_SCOPE_AGENT);
        }
        asm volatile("s_waitcnt vmcnt(0)" ::: "memory");
        __syncthreads();
    }

    // ============ W fragment: direct f32 load + f16 pack ============
    uint4 Wr[10];
    {
        const int gate = rl >> 6, unit = rl & 63;
        const int grow = gate * 256 + s * 64 + unit;
        const float* __restrict__ baseh = W_hh + grow * HID;
        const float* __restrict__ basex = W_ih + grow * NUM_CH;
#pragma unroll
        for (int j = 0; j < 10; ++j) {
            const int kh = kseg * SEGH + j * 8;
            const float* src = (kh < 256) ? (baseh + kh) : (basex + (kh - 256));
            float4 f0 = *(const float4*)(src);
            float4 f1 = *(const float4*)(src + 4);
            Wr[j] = make_uint4(pack2(f0.x, f0.y), pack2(f0.z, f0.w),
                               pack2(f1.x, f1.y), pack2(f1.z, f1.w));
        }
    }

    // producer role (tid<256): wave aq = seq, lane au = unit of slice s
    const int aq = tid >> 6;
    const int au = tid & 63;
    float bi = 0.f, bf = 0.f, bg = 0.f, bo = 0.f, c_st = 0.f;
    int xt0 = 0;
    if (tid < 256) {
        int u = s * 64 + au;
        bi = b_ih[u] + b_hh[u];
        bf = b_ih[256 + u] + b_hh[256 + u];
        bg = b_ih[512 + u] + b_hh[512 + u];
        bo = b_ih[768 + u] + b_hh[768 + u];
    }

    // gather role (tid>=256): word (peer slice sp, seq gsq, unit gu)
    const int tid2 = tid - 256;          // 0..767
    const int gp = tid2 >> 8;            // 0..2 peer index
    const int gr = tid2 & 255;
    const int gsq = gr >> 6, gu = gr & 63;
    const int sp = gp + (gp >= s ? 1 : 0);
    const unsigned int* gaddr = Hx32 + (g * MS + gsq) * HID + sp * 64 + gu;

    // zero h region of hx
    hx[tid >> 8][tid & 255] = (_Float16)0.0f;

    // producers poll tagged t0s (64 lanes same addr, s_sleep backoff), load x(0)
    if (tid < 256) {
        const unsigned int* tp = &t0s[g * MS + aq];
        unsigned int tv;
        for (;;) {
            tv = __hip_atomic_load(tp, __ATOMIC_RELAXED, __HIP_MEMORY_SCOPE_AGENT);
            if (tv & 0x80000000u) break;
            __builtin_amdgcn_s_sleep(8);
        }
        xt0 = (int)(tv & 0x7FFFFFFFu);
        hx[aq][256 + au] = (_Float16)data[xt0 * NUM_CH + au];  // x(0)
    }
    __syncthreads();

    for (int t = 0; t < PROP_LEN; ++t) {
        // producers: issue x(t+1) load EARLY (consumed after the dot; the
        // ~HBM latency hides under ~1.3us of dot compute)
        float xnext = 0.0f;
        if (tid < 256 && t + 1 < PROP_LEN)
            xnext = data[(xt0 + t + 1) * NUM_CH + au];

        // --- dot: 4 accumulator chains, broadcast LDS reads ---
        float a0 = 0.f, a1 = 0.f, a2 = 0.f, a3 = 0.f;
#pragma unroll
        for (int j = 0; j < 10; ++j) {
            const int hb = kseg * SEGH + j * 8;
            uint4 h0 = *(const uint4*)&hx[0][hb];
            uint4 h1 = *(const uint4*)&hx[1][hb];
            uint4 h2 = *(const uint4*)&hx[2][hb];
            uint4 h3 = *(const uint4*)&hx[3][hb];
            uint4 w = Wr[j];
            a0 = dot8f(w, h0, a0);
            a1 = dot8f(w, h1, a1);
            a2 = dot8f(w, h2, a2);
            a3 = dot8f(w, h3, a3);
        }
        pp[0][kseg][rl] = a0;
        pp[1][kseg][rl] = a1;
        pp[2][kseg][rl] = a2;
        pp[3][kseg][rl] = a3;
        __syncthreads();

        const unsigned int tagv = (unsigned int)(t + 1);
        const int par = (t + 1) & 1;
        if (tid < 256) {
            // --- reduce + activation + tagged publish ---
            float si = pp[aq][0][au] + pp[aq][1][au] + pp[aq][2][au] +
                       pp[aq][3][au] + bi;
            float sf = pp[aq][0][64 + au] + pp[aq][1][64 + au] +
                       pp[aq][2][64 + au] + pp[aq][3][64 + au] + bf;
            float sg = pp[aq][0][128 + au] + pp[aq][1][128 + au] +
                       pp[aq][2][128 + au] + pp[aq][3][128 + au] + bg;
            float so = pp[aq][0][192 + au] + pp[aq][1][192 + au] +
                       pp[aq][2][192 + au] + pp[aq][3][192 + au] + bo;
            float gi = fsigmoid(si), gf = fsigmoid(sf);
            float gg = ftanh(sg), go = fsigmoid(so);
            c_st = gf * c_st + gi * gg;
            float h = go * ftanh(c_st);
            HU16 hu;
            hu.h = (_Float16)h;
            __hip_atomic_store(
                &Hx32[par * HXPAR + (g * MS + aq) * HID + s * 64 + au],
                (tagv << 16) | (unsigned int)hu.u, __ATOMIC_RELAXED,
                __HIP_MEMORY_SCOPE_AGENT);
            // own slice straight into LDS (no round trip)
            hx[aq][s * 64 + au] = hu.h;
            // x(t+1): register -> LDS (load long since landed)
            if (t + 1 < PROP_LEN) hx[aq][256 + au] = (_Float16)xnext;
        } else {
            // --- gather peers' words; tag match IS the synchronization ---
            const unsigned int* ga = gaddr + par * HXPAR;
            unsigned int v =
                __hip_atomic_load(ga, __ATOMIC_RELAXED, __HIP_MEMORY_SCOPE_AGENT);
            while (__builtin_expect((v >> 16) != tagv, 0)) {
                __builtin_amdgcn_s_sleep(1);
                v = __hip_atomic_load(ga, __ATOMIC_RELAXED,
                                      __HIP_MEMORY_SCOPE_AGENT);
            }
            HU16 hv;
            hv.u = (unsigned short)(v & 0xFFFFu);
            hx[gsq][sp * 64 + gu] = hv.h;
        }
        __syncthreads();
    }

    // hx holds h_128 for all 4 seqs. Slice s computes rows [30s, 30s+30).
    if (tid < MS * 30) {
        int sq = tid / 30;
        int ml = tid % 30;
        int m = s * 30 + ml;
        const float* Wrow;
        float acc;
        int oidx;
        if (m < NUM_CLS) {
            Wrow = W_cls + m * HID;
            acc = b_cls[m];
            oidx = (g * MS + sq) * NUM_CLS + m;
        } else {
            int mb = m - NUM_CLS;
            Wrow = W_bbox + mb * HID;
            acc = b_bbox[mb];
            oidx = NUM_PROP_AFTER * NUM_CLS + (g * MS + sq) * 2 * NUM_CLS + mb;
        }
        const float4* w4 = (const float4*)Wrow;
        const _Float16* hp = &hx[sq][0];
        for (int c = 0; c < 32; ++c) {
            float4 wa = w4[c * 2 + 0];
            float4 wb = w4[c * 2 + 1];
            acc += (float)hp[c * 8 + 0] * wa.x + (float)hp[c * 8 + 1] * wa.y +
                   (float)hp[c * 8 + 2] * wa.z + (float)hp[c * 8 + 3] * wa.w +
                   (float)hp[c * 8 + 4] * wb.x + (float)hp[c * 8 + 5] * wb.y +
                   (float)hp[c * 8 + 6] * wb.z + (float)hp[c * 8 + 7] * wb.w;
        }
        out[oidx] = acc;
    }
}

extern "C" void kernel_launch(void* const* d_in, const int* in_sizes, int n_in,
                              void* d_out, int out_size, void* d_ws,
                              size_t ws_size, hipStream_t stream) {
    const float* data = (const float*)d_in[0];     // [8192, 64]
    const float* prop = (const float*)d_in[1];     // [1024, 3]
    const float* W_ih = (const float*)d_in[2];     // [1024, 64]
    const float* W_hh = (const float*)d_in[3];     // [1024, 256]
    const float* b_ih = (const float*)d_in[4];     // [1024]
    const float* b_hh = (const float*)d_in[5];     // [1024]
    const float* W_cls = (const float*)d_in[6];    // [40, 256]
    const float* b_cls = (const float*)d_in[7];    // [40]
    const float* W_bbox = (const float*)d_in[8];   // [80, 256]
    const float* b_bbox = (const float*)d_in[9];   // [80]
    float* out = (float*)d_out;

    // workspace layout
    unsigned int* t0s = (unsigned int*)d_ws;                   // [0, 1KB) tagged t0s
    unsigned int* Hx32 = (unsigned int*)((char*)d_ws + 4096);  // 512 KB tagged h (2 parities)

    // zero all tags each invocation (graph-captured, replayed per rep)
    hipMemsetAsync(d_ws, 0, 4096 + 2 * HXPAR * 4, stream);

    void* kargs[] = {(void*)&data,  (void*)&prop,   (void*)&W_ih,  (void*)&W_hh,
                     (void*)&b_ih,  (void*)&b_hh,   (void*)&W_cls, (void*)&b_cls,
                     (void*)&W_bbox, (void*)&b_bbox, (void*)&out,  (void*)&t0s,
                     (void*)&Hx32};
    hipLaunchCooperativeKernel((void*)fused_kernel, dim3(NSL * NGRP), dim3(1024),
                               kargs, 0, stream);
}